// Round 1
// baseline (38.306 us; speedup 1.0000x reference)
//
#include <hip/hip_runtime.h>
#include <math.h>

#define N_PEAKS 16

__global__ __launch_bounds__(256) void peak_transmission_kernel(
    const float* __restrict__ E,
    const float* __restrict__ ec_w, const float* __restrict__ ec_b,
    const float* __restrict__ th_w, const float* __restrict__ th_b,
    const float* __restrict__ gr_w, const float* __restrict__ gr_b,
    const float* __restrict__ gl_w, const float* __restrict__ gl_b,
    const float* __restrict__ e0,
    float* __restrict__ out, int n)
{
    __shared__ float s_ec[N_PEAKS], s_hg[N_PEAKS], s_hg2[N_PEAKS];
    __shared__ float s_nr[N_PEAKS], s_ni[N_PEAKS];

    const int tid = threadIdx.x;
    if (tid < N_PEAKS) {
        const int p = tid;
        // ec: tunable peaks are exactly p % 3 == 0 (TUNABLE = 0,3,6,9,12,15)
        float ecv = e0[p];
        if (p % 3 == 0) ecv += 0.1f * tanhf(ec_w[p] + ec_b[p]);
        // theta = pi * sigmoid(w+b)
        float theta = 3.14159265358979323846f /
                      (1.0f + expf(-(th_w[p] + th_b[p])));
        // gammas = 1e-4 + (0.5 - 1e-4) * sigmoid(w+b)
        float grv = 1e-4f + (0.5f - 1e-4f) / (1.0f + expf(-(gr_w[p] + gr_b[p])));
        float glv = 1e-4f + (0.5f - 1e-4f) / (1.0f + expf(-(gl_w[p] + gl_b[p])));
        float amp = sqrtf(grv * glv);
        float hg  = 0.5f * (grv + glv);
        s_ec[p]  = ecv;
        s_hg[p]  = hg;
        s_hg2[p] = hg * hg;
        s_nr[p]  = amp * cosf(theta);
        s_ni[p]  = amp * sinf(theta);
    }
    __syncthreads();

    // Hoist per-peak constants into registers (wave-uniform broadcast reads).
    float ec[N_PEAKS], hg2[N_PEAKS], nr[N_PEAKS], ni[N_PEAKS];
    float nihg[N_PEAKS], nrhg[N_PEAKS];
    #pragma unroll
    for (int p = 0; p < N_PEAKS; ++p) {
        ec[p]   = s_ec[p];
        hg2[p]  = s_hg2[p];
        nr[p]   = s_nr[p];
        ni[p]   = s_ni[p];
        nihg[p] = s_ni[p] * s_hg[p];
        nrhg[p] = s_nr[p] * s_hg[p];
    }

    const int gtid    = blockIdx.x * blockDim.x + threadIdx.x;
    const int stride4 = gridDim.x * blockDim.x;
    const int n4      = n >> 2;

    for (int i = gtid; i < n4; i += stride4) {
        const float4 e4 = reinterpret_cast<const float4*>(E)[i];
        const float ev[4] = {e4.x, e4.y, e4.z, e4.w};
        float o[4];
        #pragma unroll
        for (int j = 0; j < 4; ++j) {
            float ar = 0.0f, ai = 0.0f;
            #pragma unroll
            for (int p = 0; p < N_PEAKS; ++p) {
                // term = (nr + i*ni) / ((e - ec) + i*hg)
                //      = ((nr*d + ni*hg) + i*(ni*d - nr*hg)) / (d^2 + hg^2)
                float d   = ev[j] - ec[p];
                float den = __builtin_fmaf(d, d, hg2[p]);
                float inv = __builtin_amdgcn_rcpf(den);   // v_rcp_f32
                float tre = __builtin_fmaf(nr[p], d,  nihg[p]);
                float tim = __builtin_fmaf(ni[p], d, -nrhg[p]);
                ar = __builtin_fmaf(tre, inv, ar);
                ai = __builtin_fmaf(tim, inv, ai);
            }
            o[j] = ar * ar + ai * ai;
        }
        reinterpret_cast<float4*>(out)[i] =
            make_float4(o[0], o[1], o[2], o[3]);
    }

    // Scalar tail (B = 4194304 is divisible by 4, but stay robust).
    const int tail_start = n4 << 2;
    for (int i = tail_start + gtid; i < n; i += stride4) {
        float ar = 0.0f, ai = 0.0f;
        float e = E[i];
        #pragma unroll
        for (int p = 0; p < N_PEAKS; ++p) {
            float d   = e - ec[p];
            float den = __builtin_fmaf(d, d, hg2[p]);
            float inv = __builtin_amdgcn_rcpf(den);
            float tre = __builtin_fmaf(nr[p], d,  nihg[p]);
            float tim = __builtin_fmaf(ni[p], d, -nrhg[p]);
            ar = __builtin_fmaf(tre, inv, ar);
            ai = __builtin_fmaf(tim, inv, ai);
        }
        out[i] = ar * ar + ai * ai;
    }
}

extern "C" void kernel_launch(void* const* d_in, const int* in_sizes, int n_in,
                              void* d_out, int out_size, void* d_ws, size_t ws_size,
                              hipStream_t stream) {
    const float* E    = (const float*)d_in[0];
    const float* ec_w = (const float*)d_in[1];
    const float* ec_b = (const float*)d_in[2];
    const float* th_w = (const float*)d_in[3];
    const float* th_b = (const float*)d_in[4];
    const float* gr_w = (const float*)d_in[5];
    const float* gr_b = (const float*)d_in[6];
    const float* gl_w = (const float*)d_in[7];
    const float* gl_b = (const float*)d_in[8];
    const float* e0   = (const float*)d_in[9];
    // d_in[10] = tunable_mask: compile-time constant (p % 3 == 0), ignored.

    float* out = (float*)d_out;
    const int n = in_sizes[0];  // BATCH

    const int block = 256;
    const int n4 = n >> 2;
    int grid = (n4 + block - 1) / block;
    if (grid > 2048) grid = 2048;
    if (grid < 1) grid = 1;

    peak_transmission_kernel<<<grid, block, 0, stream>>>(
        E, ec_w, ec_b, th_w, th_b, gr_w, gr_b, gl_w, gl_b, e0, out, n);
}

// Round 2
// 37.395 us; speedup vs baseline: 1.0244x; 1.0244x over previous
//
#include <hip/hip_runtime.h>
#include <math.h>

#define N_PEAKS 16

// Force a wave-uniform float into an SGPR.
__device__ __forceinline__ float rfl(float x) {
    return __builtin_bit_cast(float,
        __builtin_amdgcn_readfirstlane(__builtin_bit_cast(int, x)));
}

__global__ __launch_bounds__(256, 4) void peak_transmission_kernel(
    const float* __restrict__ E,
    const float* __restrict__ ec_w, const float* __restrict__ ec_b,
    const float* __restrict__ th_w, const float* __restrict__ th_b,
    const float* __restrict__ gr_w, const float* __restrict__ gr_b,
    const float* __restrict__ gl_w, const float* __restrict__ gl_b,
    const float* __restrict__ e0,
    float* __restrict__ out, int n)
{
    __shared__ float s_ec[N_PEAKS], s_hg[N_PEAKS], s_hg2[N_PEAKS];
    __shared__ float s_nr[N_PEAKS], s_ni[N_PEAKS];

    const int tid = threadIdx.x;
    if (tid < N_PEAKS) {
        const int p = tid;
        // TUNABLE = {0,3,6,9,12,15} == (p % 3 == 0)
        float ecv = e0[p];
        if (p % 3 == 0) ecv += 0.1f * tanhf(ec_w[p] + ec_b[p]);
        float theta = 3.14159265358979323846f /
                      (1.0f + expf(-(th_w[p] + th_b[p])));
        float grv = 1e-4f + (0.5f - 1e-4f) / (1.0f + expf(-(gr_w[p] + gr_b[p])));
        float glv = 1e-4f + (0.5f - 1e-4f) / (1.0f + expf(-(gl_w[p] + gl_b[p])));
        float amp = sqrtf(grv * glv);
        float hg  = 0.5f * (grv + glv);
        s_ec[p]  = ecv;
        s_hg[p]  = hg;
        s_hg2[p] = hg * hg;
        s_nr[p]  = amp * cosf(theta);
        s_ni[p]  = amp * sinf(theta);
    }
    __syncthreads();

    // Per-peak constants -> SGPRs (wave-uniform). 5 x 16 = 80 scalars.
    float ec[N_PEAKS], hg2[N_PEAKS], hg[N_PEAKS], nr[N_PEAKS], ni[N_PEAKS];
    #pragma unroll
    for (int p = 0; p < N_PEAKS; ++p) {
        ec[p]  = rfl(s_ec[p]);
        hg2[p] = rfl(s_hg2[p]);
        hg[p]  = rfl(s_hg[p]);
        nr[p]  = rfl(s_nr[p]);
        ni[p]  = rfl(s_ni[p]);
    }

    const int gtid    = blockIdx.x * blockDim.x + threadIdx.x;
    const int stride4 = gridDim.x * blockDim.x;
    const int n4      = n >> 2;

    for (int i = gtid; i < n4; i += stride4) {
        const float4 e4 = reinterpret_cast<const float4*>(E)[i];
        float ev[4] = {e4.x, e4.y, e4.z, e4.w};
        float ar[4] = {0.f, 0.f, 0.f, 0.f};
        float ai[4] = {0.f, 0.f, 0.f, 0.f};
        // p outer / j inner: 4 independent rcp chains per peak,
        // each VALU op reads at most ONE scalar operand.
        #pragma unroll
        for (int p = 0; p < N_PEAKS; ++p) {
            #pragma unroll
            for (int j = 0; j < 4; ++j) {
                float d   = ev[j] - ec[p];                    // 1 sgpr
                float den = __builtin_fmaf(d, d, hg2[p]);     // 1 sgpr
                float inv = __builtin_amdgcn_rcpf(den);       // trans pipe
                float x   = d * inv;                          // 0 sgpr
                float y   = hg[p] * inv;                      // 1 sgpr
                ar[j] = __builtin_fmaf(nr[p], x, ar[j]);      // 1 sgpr
                ar[j] = __builtin_fmaf(ni[p], y, ar[j]);      // 1 sgpr
                ai[j] = __builtin_fmaf(ni[p], x, ai[j]);      // 1 sgpr
                ai[j] = __builtin_fmaf(-nr[p], y, ai[j]);     // neg = modifier
            }
        }
        float4 o4;
        o4.x = __builtin_fmaf(ar[0], ar[0], ai[0] * ai[0]);
        o4.y = __builtin_fmaf(ar[1], ar[1], ai[1] * ai[1]);
        o4.z = __builtin_fmaf(ar[2], ar[2], ai[2] * ai[2]);
        o4.w = __builtin_fmaf(ar[3], ar[3], ai[3] * ai[3]);
        reinterpret_cast<float4*>(out)[i] = o4;
    }

    // Scalar tail (BATCH is divisible by 4; robustness only).
    const int tail_start = n4 << 2;
    for (int i = tail_start + gtid; i < n; i += stride4) {
        float e = E[i];
        float ar = 0.f, ai = 0.f;
        #pragma unroll
        for (int p = 0; p < N_PEAKS; ++p) {
            float d   = e - ec[p];
            float den = __builtin_fmaf(d, d, hg2[p]);
            float inv = __builtin_amdgcn_rcpf(den);
            float x   = d * inv;
            float y   = hg[p] * inv;
            ar = __builtin_fmaf(nr[p], x, ar);
            ar = __builtin_fmaf(ni[p], y, ar);
            ai = __builtin_fmaf(ni[p], x, ai);
            ai = __builtin_fmaf(-nr[p], y, ai);
        }
        out[i] = __builtin_fmaf(ar, ar, ai * ai);
    }
}

extern "C" void kernel_launch(void* const* d_in, const int* in_sizes, int n_in,
                              void* d_out, int out_size, void* d_ws, size_t ws_size,
                              hipStream_t stream) {
    const float* E    = (const float*)d_in[0];
    const float* ec_w = (const float*)d_in[1];
    const float* ec_b = (const float*)d_in[2];
    const float* th_w = (const float*)d_in[3];
    const float* th_b = (const float*)d_in[4];
    const float* gr_w = (const float*)d_in[5];
    const float* gr_b = (const float*)d_in[6];
    const float* gl_w = (const float*)d_in[7];
    const float* gl_b = (const float*)d_in[8];
    const float* e0   = (const float*)d_in[9];
    // d_in[10] = tunable_mask: compile-time constant (p % 3 == 0), ignored.

    float* out = (float*)d_out;
    const int n = in_sizes[0];  // BATCH

    const int block = 256;
    const int n4 = n >> 2;
    int grid = (n4 + block - 1) / block;
    if (grid > 2048) grid = 2048;
    if (grid < 1) grid = 1;

    peak_transmission_kernel<<<grid, block, 0, stream>>>(
        E, ec_w, ec_b, th_w, th_b, gr_w, gr_b, gl_w, gl_b, e0, out, n);
}

// Round 3
// 22.063 us; speedup vs baseline: 1.7362x; 1.6949x over previous
//
#include <hip/hip_runtime.h>
#include <math.h>

#define N_PEAKS 16

typedef float f32x4 __attribute__((ext_vector_type(4)));

// Force a wave-uniform float into an SGPR.
__device__ __forceinline__ float rfl(float x) {
    return __builtin_bit_cast(float,
        __builtin_amdgcn_readfirstlane(__builtin_bit_cast(int, x)));
}

// Shared preamble: per-peak scalar params -> LDS.
__device__ __forceinline__ void compute_peak_consts(
    const float* __restrict__ ec_w, const float* __restrict__ ec_b,
    const float* __restrict__ th_w, const float* __restrict__ th_b,
    const float* __restrict__ gr_w, const float* __restrict__ gr_b,
    const float* __restrict__ gl_w, const float* __restrict__ gl_b,
    const float* __restrict__ e0,
    float* s_ec, float* s_hg2, float* s_nr, float* s_ni,
    float* s_nihg, float* s_mnrhg)
{
    const int p = threadIdx.x;
    if (p < N_PEAKS) {
        // TUNABLE = {0,3,6,9,12,15} == (p % 3 == 0)
        float ecv = e0[p];
        if (p % 3 == 0) ecv += 0.1f * tanhf(ec_w[p] + ec_b[p]);
        float theta = 3.14159265358979323846f /
                      (1.0f + expf(-(th_w[p] + th_b[p])));
        float grv = 1e-4f + (0.5f - 1e-4f) / (1.0f + expf(-(gr_w[p] + gr_b[p])));
        float glv = 1e-4f + (0.5f - 1e-4f) / (1.0f + expf(-(gl_w[p] + gl_b[p])));
        float amp = sqrtf(grv * glv);
        float hg  = 0.5f * (grv + glv);
        float nr  = amp * cosf(theta);
        float ni  = amp * sinf(theta);
        s_ec[p]    = ecv;
        s_hg2[p]   = hg * hg;
        s_nr[p]    = nr;
        s_ni[p]    = ni;
        s_nihg[p]  = ni * hg;
        s_mnrhg[p] = -nr * hg;
    }
    __syncthreads();
}

// ---------------------------------------------------------------------------
// Exact-shape kernel: grid*block*CHUNKS float4s == n4 exactly. Each thread
// loads CHUNKS float4s up front (deep memory-level parallelism), then
// computes. Peaks merged in pairs over a common real denominator:
//   t1 + t2 = (tre1*D2 + tre2*D1) / (D1*D2)   -> 1 rcp per 2 peaks.
// Every VALU op reads at most ONE scalar(SGPR) operand; nihg/mnrhg live in
// VGPRs so the 2-constant FMAs stay legal without v_mov copies.
// ---------------------------------------------------------------------------
__global__ __launch_bounds__(256, 4) void peak_kernel_exact(
    const float* __restrict__ E,
    const float* __restrict__ ec_w, const float* __restrict__ ec_b,
    const float* __restrict__ th_w, const float* __restrict__ th_b,
    const float* __restrict__ gr_w, const float* __restrict__ gr_b,
    const float* __restrict__ gl_w, const float* __restrict__ gl_b,
    const float* __restrict__ e0,
    float* __restrict__ out)
{
    __shared__ float s_ec[N_PEAKS], s_hg2[N_PEAKS], s_nr[N_PEAKS],
                     s_ni[N_PEAKS], s_nihg[N_PEAKS], s_mnrhg[N_PEAKS];
    compute_peak_consts(ec_w, ec_b, th_w, th_b, gr_w, gr_b, gl_w, gl_b, e0,
                        s_ec, s_hg2, s_nr, s_ni, s_nihg, s_mnrhg);

    // SGPR constants (wave-uniform).
    float ec_s[N_PEAKS], hg2_s[N_PEAKS], nr_s[N_PEAKS], ni_s[N_PEAKS];
    // VGPR constants (second operand of the 2-const FMAs).
    float nihg_v[N_PEAKS], mnrhg_v[N_PEAKS];
    #pragma unroll
    for (int p = 0; p < N_PEAKS; ++p) {
        ec_s[p]   = rfl(s_ec[p]);
        hg2_s[p]  = rfl(s_hg2[p]);
        nr_s[p]   = rfl(s_nr[p]);
        ni_s[p]   = rfl(s_ni[p]);
        nihg_v[p]  = s_nihg[p];
        mnrhg_v[p] = s_mnrhg[p];
    }

    const int g      = blockIdx.x * blockDim.x + threadIdx.x;
    const int stride = gridDim.x * blockDim.x;
    const f32x4* E4  = reinterpret_cast<const f32x4*>(E);
    f32x4* O4        = reinterpret_cast<f32x4*>(out);

    // Issue all 4 loads before any compute (64B of MLP per lane).
    f32x4 v0 = E4[g + 0 * stride];
    f32x4 v1 = E4[g + 1 * stride];
    f32x4 v2 = E4[g + 2 * stride];
    f32x4 v3 = E4[g + 3 * stride];
    f32x4 vin[4] = {v0, v1, v2, v3};

    #pragma unroll
    for (int c = 0; c < 4; ++c) {
        float ev[4] = {vin[c][0], vin[c][1], vin[c][2], vin[c][3]};
        float ar[4] = {0.f, 0.f, 0.f, 0.f};
        float ai[4] = {0.f, 0.f, 0.f, 0.f};
        #pragma unroll
        for (int q = 0; q < N_PEAKS / 2; ++q) {
            const int p1 = 2 * q, p2 = 2 * q + 1;
            #pragma unroll
            for (int j = 0; j < 4; ++j) {
                float d1 = ev[j] - ec_s[p1];                       // 1 sgpr
                float d2 = ev[j] - ec_s[p2];                       // 1 sgpr
                float D1 = __builtin_fmaf(d1, d1, hg2_s[p1]);      // 1 sgpr
                float D2 = __builtin_fmaf(d2, d2, hg2_s[p2]);      // 1 sgpr
                float t1 = __builtin_fmaf(nr_s[p1], d1, nihg_v[p1]);
                float u1 = __builtin_fmaf(ni_s[p1], d1, mnrhg_v[p1]);
                float t2 = __builtin_fmaf(nr_s[p2], d2, nihg_v[p2]);
                float u2 = __builtin_fmaf(ni_s[p2], d2, mnrhg_v[p2]);
                float P   = D1 * D2;
                float inv = __builtin_amdgcn_rcpf(P);              // 1 rcp / 2 peaks
                float NR  = __builtin_fmaf(t2, D1, t1 * D2);
                float NI  = __builtin_fmaf(u2, D1, u1 * D2);
                ar[j] = __builtin_fmaf(NR, inv, ar[j]);
                ai[j] = __builtin_fmaf(NI, inv, ai[j]);
            }
        }
        f32x4 o;
        o[0] = __builtin_fmaf(ar[0], ar[0], ai[0] * ai[0]);
        o[1] = __builtin_fmaf(ar[1], ar[1], ai[1] * ai[1]);
        o[2] = __builtin_fmaf(ar[2], ar[2], ai[2] * ai[2]);
        o[3] = __builtin_fmaf(ar[3], ar[3], ai[3] * ai[3]);
        __builtin_nontemporal_store(o, &O4[g + c * stride]);
    }
}

// ---------------------------------------------------------------------------
// Generic fallback (any n): grid-stride float4 + scalar tail, same pair math.
// ---------------------------------------------------------------------------
__global__ __launch_bounds__(256, 4) void peak_kernel_generic(
    const float* __restrict__ E,
    const float* __restrict__ ec_w, const float* __restrict__ ec_b,
    const float* __restrict__ th_w, const float* __restrict__ th_b,
    const float* __restrict__ gr_w, const float* __restrict__ gr_b,
    const float* __restrict__ gl_w, const float* __restrict__ gl_b,
    const float* __restrict__ e0,
    float* __restrict__ out, int n)
{
    __shared__ float s_ec[N_PEAKS], s_hg2[N_PEAKS], s_nr[N_PEAKS],
                     s_ni[N_PEAKS], s_nihg[N_PEAKS], s_mnrhg[N_PEAKS];
    compute_peak_consts(ec_w, ec_b, th_w, th_b, gr_w, gr_b, gl_w, gl_b, e0,
                        s_ec, s_hg2, s_nr, s_ni, s_nihg, s_mnrhg);

    float ec_s[N_PEAKS], hg2_s[N_PEAKS], nr_s[N_PEAKS], ni_s[N_PEAKS];
    float nihg_v[N_PEAKS], mnrhg_v[N_PEAKS];
    #pragma unroll
    for (int p = 0; p < N_PEAKS; ++p) {
        ec_s[p]   = rfl(s_ec[p]);
        hg2_s[p]  = rfl(s_hg2[p]);
        nr_s[p]   = rfl(s_nr[p]);
        ni_s[p]   = rfl(s_ni[p]);
        nihg_v[p]  = s_nihg[p];
        mnrhg_v[p] = s_mnrhg[p];
    }

    const int gtid    = blockIdx.x * blockDim.x + threadIdx.x;
    const int stride  = gridDim.x * blockDim.x;
    const int n4      = n >> 2;
    const f32x4* E4   = reinterpret_cast<const f32x4*>(E);
    f32x4* O4         = reinterpret_cast<f32x4*>(out);

    for (int i = gtid; i < n4; i += stride) {
        f32x4 e4 = E4[i];
        float ev[4] = {e4[0], e4[1], e4[2], e4[3]};
        float ar[4] = {0.f, 0.f, 0.f, 0.f};
        float ai[4] = {0.f, 0.f, 0.f, 0.f};
        #pragma unroll
        for (int q = 0; q < N_PEAKS / 2; ++q) {
            const int p1 = 2 * q, p2 = 2 * q + 1;
            #pragma unroll
            for (int j = 0; j < 4; ++j) {
                float d1 = ev[j] - ec_s[p1];
                float d2 = ev[j] - ec_s[p2];
                float D1 = __builtin_fmaf(d1, d1, hg2_s[p1]);
                float D2 = __builtin_fmaf(d2, d2, hg2_s[p2]);
                float t1 = __builtin_fmaf(nr_s[p1], d1, nihg_v[p1]);
                float u1 = __builtin_fmaf(ni_s[p1], d1, mnrhg_v[p1]);
                float t2 = __builtin_fmaf(nr_s[p2], d2, nihg_v[p2]);
                float u2 = __builtin_fmaf(ni_s[p2], d2, mnrhg_v[p2]);
                float P   = D1 * D2;
                float inv = __builtin_amdgcn_rcpf(P);
                float NR  = __builtin_fmaf(t2, D1, t1 * D2);
                float NI  = __builtin_fmaf(u2, D1, u1 * D2);
                ar[j] = __builtin_fmaf(NR, inv, ar[j]);
                ai[j] = __builtin_fmaf(NI, inv, ai[j]);
            }
        }
        f32x4 o;
        o[0] = __builtin_fmaf(ar[0], ar[0], ai[0] * ai[0]);
        o[1] = __builtin_fmaf(ar[1], ar[1], ai[1] * ai[1]);
        o[2] = __builtin_fmaf(ar[2], ar[2], ai[2] * ai[2]);
        o[3] = __builtin_fmaf(ar[3], ar[3], ai[3] * ai[3]);
        O4[i] = o;
    }

    const int tail_start = n4 << 2;
    for (int i = tail_start + gtid; i < n; i += stride) {
        float e = E[i];
        float ar = 0.f, ai = 0.f;
        #pragma unroll
        for (int q = 0; q < N_PEAKS / 2; ++q) {
            const int p1 = 2 * q, p2 = 2 * q + 1;
            float d1 = e - ec_s[p1];
            float d2 = e - ec_s[p2];
            float D1 = __builtin_fmaf(d1, d1, hg2_s[p1]);
            float D2 = __builtin_fmaf(d2, d2, hg2_s[p2]);
            float t1 = __builtin_fmaf(nr_s[p1], d1, nihg_v[p1]);
            float u1 = __builtin_fmaf(ni_s[p1], d1, mnrhg_v[p1]);
            float t2 = __builtin_fmaf(nr_s[p2], d2, nihg_v[p2]);
            float u2 = __builtin_fmaf(ni_s[p2], d2, mnrhg_v[p2]);
            float P   = D1 * D2;
            float inv = __builtin_amdgcn_rcpf(P);
            float NR  = __builtin_fmaf(t2, D1, t1 * D2);
            float NI  = __builtin_fmaf(u2, D1, u1 * D2);
            ar = __builtin_fmaf(NR, inv, ar);
            ai = __builtin_fmaf(NI, inv, ai);
        }
        out[i] = __builtin_fmaf(ar, ar, ai * ai);
    }
}

extern "C" void kernel_launch(void* const* d_in, const int* in_sizes, int n_in,
                              void* d_out, int out_size, void* d_ws, size_t ws_size,
                              hipStream_t stream) {
    const float* E    = (const float*)d_in[0];
    const float* ec_w = (const float*)d_in[1];
    const float* ec_b = (const float*)d_in[2];
    const float* th_w = (const float*)d_in[3];
    const float* th_b = (const float*)d_in[4];
    const float* gr_w = (const float*)d_in[5];
    const float* gr_b = (const float*)d_in[6];
    const float* gl_w = (const float*)d_in[7];
    const float* gl_b = (const float*)d_in[8];
    const float* e0   = (const float*)d_in[9];
    // d_in[10] = tunable_mask: compile-time constant (p % 3 == 0), ignored.

    float* out = (float*)d_out;
    const int n = in_sizes[0];  // BATCH

    const int block  = 256;
    const int CHUNKS = 4;

    if ((n & 3) == 0) {
        const int n4 = n >> 2;
        const int per_block = block * CHUNKS;       // float4s per block
        if (n4 % per_block == 0) {
            const int grid = n4 / per_block;        // 1024 for BATCH=4194304
            peak_kernel_exact<<<grid, block, 0, stream>>>(
                E, ec_w, ec_b, th_w, th_b, gr_w, gr_b, gl_w, gl_b, e0, out);
            return;
        }
    }

    int grid = ((n >> 2) + block - 1) / block;
    if (grid > 2048) grid = 2048;
    if (grid < 1) grid = 1;
    peak_kernel_generic<<<grid, block, 0, stream>>>(
        E, ec_w, ec_b, th_w, th_b, gr_w, gr_b, gl_w, gl_b, e0, out, n);
}

// Round 4
// 17.445 us; speedup vs baseline: 2.1959x; 1.2647x over previous
//
#include <hip/hip_runtime.h>
#include <math.h>

#define N_PEAKS 16
#define N_PAIRS 8

typedef float f32x4 __attribute__((ext_vector_type(4)));

// Force a wave-uniform float into an SGPR (used by generic fallback only).
__device__ __forceinline__ float rfl(float x) {
    return __builtin_bit_cast(float,
        __builtin_amdgcn_readfirstlane(__builtin_bit_cast(int, x)));
}

// Per-peak scalar params -> pair-major LDS layout:
// s_pc4[q*3+0] = {ec1, ec2, hg2_1, hg2_2}
// s_pc4[q*3+1] = {nr1, nr2, ni1, ni2}
// s_pc4[q*3+2] = {nihg1, nihg2, -nrhg1, -nrhg2}
__device__ __forceinline__ void compute_pair_consts(
    const float* __restrict__ ec_w, const float* __restrict__ ec_b,
    const float* __restrict__ th_w, const float* __restrict__ th_b,
    const float* __restrict__ gr_w, const float* __restrict__ gr_b,
    const float* __restrict__ gl_w, const float* __restrict__ gl_b,
    const float* __restrict__ e0, float* s_pc)
{
    const int p = threadIdx.x;
    if (p < N_PEAKS) {
        // TUNABLE = {0,3,6,9,12,15} == (p % 3 == 0)
        float ecv = e0[p];
        if (p % 3 == 0) ecv += 0.1f * tanhf(ec_w[p] + ec_b[p]);
        float theta = 3.14159265358979323846f /
                      (1.0f + expf(-(th_w[p] + th_b[p])));
        float grv = 1e-4f + (0.5f - 1e-4f) / (1.0f + expf(-(gr_w[p] + gr_b[p])));
        float glv = 1e-4f + (0.5f - 1e-4f) / (1.0f + expf(-(gl_w[p] + gl_b[p])));
        float amp = sqrtf(grv * glv);
        float hg  = 0.5f * (grv + glv);
        float nr  = amp * cosf(theta);
        float ni  = amp * sinf(theta);
        float* base = s_pc + (p >> 1) * 12;
        const int s = p & 1;
        base[0 + s]  = ecv;
        base[2 + s]  = hg * hg;
        base[4 + s]  = nr;
        base[6 + s]  = ni;
        base[8 + s]  = ni * hg;
        base[10 + s] = -nr * hg;
    }
    __syncthreads();
}

// ---------------------------------------------------------------------------
// Exact-shape kernel: each thread owns 8 elements (2 float4s), grid covers n
// exactly. Small code: the pair loop is kept DYNAMIC (unroll 1) with
// constants broadcast from LDS (3x ds_read_b128, same-address = conflict
// free) and a one-iteration register prefetch. 8 independent rcp chains.
// ---------------------------------------------------------------------------
__global__ __launch_bounds__(256, 4) void peak_kernel8(
    const float* __restrict__ E,
    const float* __restrict__ ec_w, const float* __restrict__ ec_b,
    const float* __restrict__ th_w, const float* __restrict__ th_b,
    const float* __restrict__ gr_w, const float* __restrict__ gr_b,
    const float* __restrict__ gl_w, const float* __restrict__ gl_b,
    const float* __restrict__ e0,
    float* __restrict__ out)
{
    __shared__ f32x4 s_pc4[N_PAIRS * 3];
    compute_pair_consts(ec_w, ec_b, th_w, th_b, gr_w, gr_b, gl_w, gl_b, e0,
                        reinterpret_cast<float*>(s_pc4));

    const int g      = blockIdx.x * blockDim.x + threadIdx.x;
    const int stride = gridDim.x * blockDim.x;
    const f32x4* E4  = reinterpret_cast<const f32x4*>(E);
    f32x4* O4        = reinterpret_cast<f32x4*>(out);

    // Two coalesced sweeps, both loads in flight before any compute.
    const f32x4 ea = E4[g];
    const f32x4 eb = E4[g + stride];

    float ev[8] = {ea[0], ea[1], ea[2], ea[3], eb[0], eb[1], eb[2], eb[3]};
    float ar[8] = {0.f, 0.f, 0.f, 0.f, 0.f, 0.f, 0.f, 0.f};
    float ai[8] = {0.f, 0.f, 0.f, 0.f, 0.f, 0.f, 0.f, 0.f};

    // Prefetch pair 0 constants.
    f32x4 nA = s_pc4[0], nB = s_pc4[1], nC = s_pc4[2];

    #pragma unroll 1
    for (int q = 0; q < N_PAIRS; ++q) {
        const f32x4 cA = nA, cB = nB, cC = nC;
        const int qn = (q + 1 < N_PAIRS) ? (q + 1) : (N_PAIRS - 1);
        nA = s_pc4[qn * 3 + 0];   // issued early; first use is next iter
        nB = s_pc4[qn * 3 + 1];
        nC = s_pc4[qn * 3 + 2];
        #pragma unroll
        for (int j = 0; j < 8; ++j) {
            float d1 = ev[j] - cA[0];
            float d2 = ev[j] - cA[1];
            float D1 = __builtin_fmaf(d1, d1, cA[2]);
            float D2 = __builtin_fmaf(d2, d2, cA[3]);
            float t1 = __builtin_fmaf(cB[0], d1, cC[0]);
            float u1 = __builtin_fmaf(cB[2], d1, cC[2]);
            float t2 = __builtin_fmaf(cB[1], d2, cC[1]);
            float u2 = __builtin_fmaf(cB[3], d2, cC[3]);
            float P   = D1 * D2;
            float inv = __builtin_amdgcn_rcpf(P);     // 1 rcp per 2 peaks
            float NR  = __builtin_fmaf(t2, D1, t1 * D2);
            float NI  = __builtin_fmaf(u2, D1, u1 * D2);
            ar[j] = __builtin_fmaf(NR, inv, ar[j]);
            ai[j] = __builtin_fmaf(NI, inv, ai[j]);
        }
    }

    f32x4 oa, ob;
    #pragma unroll
    for (int j = 0; j < 4; ++j) {
        oa[j] = __builtin_fmaf(ar[j], ar[j], ai[j] * ai[j]);
        ob[j] = __builtin_fmaf(ar[j + 4], ar[j + 4], ai[j + 4] * ai[j + 4]);
    }
    __builtin_nontemporal_store(oa, &O4[g]);
    __builtin_nontemporal_store(ob, &O4[g + stride]);
}

// ---------------------------------------------------------------------------
// Generic fallback (any n): round-3 kernel, known correct. Not used for the
// benchmark shape.
// ---------------------------------------------------------------------------
__global__ __launch_bounds__(256, 4) void peak_kernel_generic(
    const float* __restrict__ E,
    const float* __restrict__ ec_w, const float* __restrict__ ec_b,
    const float* __restrict__ th_w, const float* __restrict__ th_b,
    const float* __restrict__ gr_w, const float* __restrict__ gr_b,
    const float* __restrict__ gl_w, const float* __restrict__ gl_b,
    const float* __restrict__ e0,
    float* __restrict__ out, int n)
{
    __shared__ f32x4 s_pc4[N_PAIRS * 3];
    compute_pair_consts(ec_w, ec_b, th_w, th_b, gr_w, gr_b, gl_w, gl_b, e0,
                        reinterpret_cast<float*>(s_pc4));

    // Constants to registers (uniform VGPR values).
    float ecv[N_PEAKS], hg2[N_PEAKS], nrv[N_PEAKS], niv[N_PEAKS];
    float nihg[N_PEAKS], mnrhg[N_PEAKS];
    #pragma unroll
    for (int q = 0; q < N_PAIRS; ++q) {
        f32x4 cA = s_pc4[q * 3 + 0], cB = s_pc4[q * 3 + 1],
              cC = s_pc4[q * 3 + 2];
        ecv[2*q] = cA[0];   ecv[2*q+1] = cA[1];
        hg2[2*q] = cA[2];   hg2[2*q+1] = cA[3];
        nrv[2*q] = cB[0];   nrv[2*q+1] = cB[1];
        niv[2*q] = cB[2];   niv[2*q+1] = cB[3];
        nihg[2*q] = cC[0];  nihg[2*q+1] = cC[1];
        mnrhg[2*q] = cC[2]; mnrhg[2*q+1] = cC[3];
    }

    const int gtid   = blockIdx.x * blockDim.x + threadIdx.x;
    const int stride = gridDim.x * blockDim.x;
    const int n4     = n >> 2;
    const f32x4* E4  = reinterpret_cast<const f32x4*>(E);
    f32x4* O4        = reinterpret_cast<f32x4*>(out);

    for (int i = gtid; i < n4; i += stride) {
        f32x4 e4 = E4[i];
        float ar[4] = {0.f, 0.f, 0.f, 0.f};
        float ai[4] = {0.f, 0.f, 0.f, 0.f};
        #pragma unroll
        for (int q = 0; q < N_PAIRS; ++q) {
            const int p1 = 2 * q, p2 = 2 * q + 1;
            #pragma unroll
            for (int j = 0; j < 4; ++j) {
                float d1 = e4[j] - ecv[p1];
                float d2 = e4[j] - ecv[p2];
                float D1 = __builtin_fmaf(d1, d1, hg2[p1]);
                float D2 = __builtin_fmaf(d2, d2, hg2[p2]);
                float t1 = __builtin_fmaf(nrv[p1], d1, nihg[p1]);
                float u1 = __builtin_fmaf(niv[p1], d1, mnrhg[p1]);
                float t2 = __builtin_fmaf(nrv[p2], d2, nihg[p2]);
                float u2 = __builtin_fmaf(niv[p2], d2, mnrhg[p2]);
                float P   = D1 * D2;
                float inv = __builtin_amdgcn_rcpf(P);
                float NR  = __builtin_fmaf(t2, D1, t1 * D2);
                float NI  = __builtin_fmaf(u2, D1, u1 * D2);
                ar[j] = __builtin_fmaf(NR, inv, ar[j]);
                ai[j] = __builtin_fmaf(NI, inv, ai[j]);
            }
        }
        f32x4 o;
        #pragma unroll
        for (int j = 0; j < 4; ++j)
            o[j] = __builtin_fmaf(ar[j], ar[j], ai[j] * ai[j]);
        O4[i] = o;
    }

    const int tail_start = n4 << 2;
    for (int i = tail_start + gtid; i < n; i += stride) {
        float e = E[i];
        float ar = 0.f, ai = 0.f;
        #pragma unroll
        for (int q = 0; q < N_PAIRS; ++q) {
            const int p1 = 2 * q, p2 = 2 * q + 1;
            float d1 = e - ecv[p1];
            float d2 = e - ecv[p2];
            float D1 = __builtin_fmaf(d1, d1, hg2[p1]);
            float D2 = __builtin_fmaf(d2, d2, hg2[p2]);
            float t1 = __builtin_fmaf(nrv[p1], d1, nihg[p1]);
            float u1 = __builtin_fmaf(niv[p1], d1, mnrhg[p1]);
            float t2 = __builtin_fmaf(nrv[p2], d2, nihg[p2]);
            float u2 = __builtin_fmaf(niv[p2], d2, mnrhg[p2]);
            float P   = D1 * D2;
            float inv = __builtin_amdgcn_rcpf(P);
            float NR  = __builtin_fmaf(t2, D1, t1 * D2);
            float NI  = __builtin_fmaf(u2, D1, u1 * D2);
            ar = __builtin_fmaf(NR, inv, ar);
            ai = __builtin_fmaf(NI, inv, ai);
        }
        out[i] = __builtin_fmaf(ar, ar, ai * ai);
    }
}

extern "C" void kernel_launch(void* const* d_in, const int* in_sizes, int n_in,
                              void* d_out, int out_size, void* d_ws, size_t ws_size,
                              hipStream_t stream) {
    const float* E    = (const float*)d_in[0];
    const float* ec_w = (const float*)d_in[1];
    const float* ec_b = (const float*)d_in[2];
    const float* th_w = (const float*)d_in[3];
    const float* th_b = (const float*)d_in[4];
    const float* gr_w = (const float*)d_in[5];
    const float* gr_b = (const float*)d_in[6];
    const float* gl_w = (const float*)d_in[7];
    const float* gl_b = (const float*)d_in[8];
    const float* e0   = (const float*)d_in[9];
    // d_in[10] = tunable_mask: compile-time constant (p % 3 == 0), ignored.

    float* out = (float*)d_out;
    const int n = in_sizes[0];  // BATCH

    const int block = 256;
    const int ELEMS_PER_THREAD = 8;   // 2 x float4

    if ((n & 3) == 0) {
        const int n4 = n >> 2;
        const int per_block = block * (ELEMS_PER_THREAD / 4);
        if (n4 % per_block == 0) {
            const int grid = n4 / per_block;   // 2048 for BATCH=4194304
            peak_kernel8<<<grid, block, 0, stream>>>(
                E, ec_w, ec_b, th_w, th_b, gr_w, gr_b, gl_w, gl_b, e0, out);
            return;
        }
    }

    int grid = ((n >> 2) + block - 1) / block;
    if (grid > 2048) grid = 2048;
    if (grid < 1) grid = 1;
    peak_kernel_generic<<<grid, block, 0, stream>>>(
        E, ec_w, ec_b, th_w, th_b, gr_w, gr_b, gl_w, gl_b, e0, out, n);
}